// Round 1
// baseline (90.309 us; speedup 1.0000x reference)
//
#include <hip/hip_runtime.h>

// GraphProjection, round 4: kill the LDS round-trip.
//
// Previous structure staged all 960 blended channels through LDS purely to
// re-align the +3-float coord offset for 16B global stores.  Those scalar
// ds_writes were lane-stride-16B => 8-way bank conflict (~3x LDS cost), plus
// a second barrier and a full LDS read-back.
//
// Key fact: level boundaries in the channel dim (64/192/448) are 4-aligned,
// so a 4-channel output group NEVER spans two levels.  The only misalignment
// is the constant +3 coord offset, and gfx9+ global memory supports
// 4B-aligned dwordx4.  So: blend in registers, store feature float4s
// directly to global as (4B-aligned) nontemporal stores; 12 spare phase-0
// lanes write the coord floats.  No feature LDS at all.
//
// Each lane handles 8 channels/iteration (2x float4 per corner, 32B-aligned
// loads) to halve index math and LDS broadcast reads.

#define PTS  4
#define ROWF 963   // 3 coords + 960 samples
#define GP2  120   // 8-float groups per point (960/8)

typedef float fx4  __attribute__((ext_vector_type(4)));
typedef float fx4u __attribute__((ext_vector_type(4), aligned(4)));

static __device__ __forceinline__ fx4 blend4(const float4 w,
                                             const fx4 a, const fx4 b,
                                             const fx4 c, const fx4 d) {
    fx4 r;
    r.x = w.x * a.x + w.y * b.x + w.z * c.x + w.w * d.x;
    r.y = w.x * a.y + w.y * b.y + w.z * c.y + w.w * d.y;
    r.z = w.x * a.z + w.y * b.z + w.z * c.z + w.w * d.z;
    r.w = w.x * a.w + w.y * b.w + w.z * c.w + w.w * d.w;
    return r;
}

__global__ __launch_bounds__(256) void graphproj_kernel(
    const float* __restrict__ coords,
    const float* __restrict__ f1, const float* __restrict__ f2,
    const float* __restrict__ f3, const float* __restrict__ f4,
    float* __restrict__ out, int N)
{
    __shared__ __align__(16) float s_w[PTS][4][4];   // w11,w21,w12,w22
    __shared__ const float* s_q[PTS][4][4];          // corner ptrs

    const int b  = blockIdx.x;
    const int t  = threadIdx.x;
    const int p0 = b * PTS;
    const int npts = min(PTS, N - p0);

    // ---- phase 0: weights + corner pointers (16 lanes) ----
    if (t < 4 * npts) {
        const int pt = t >> 2;
        const int lv = t & 3;
        const int p  = p0 + pt;
        const float X = coords[p * 3 + 0];
        const float Y = coords[p * 3 + 1];
        const float Z = coords[p * 3 + 2];
        float h = 250.0f * (-Y) / (-Z) + 112.0f;
        float w = 250.0f * X / (-Z) + 112.0f;
        h = fminf(fmaxf(h, 0.0f), 223.0f);
        w = fminf(fmaxf(w, 0.0f), 223.0f);

        const int H = (lv == 0) ? 56 : (lv == 1) ? 28 : (lv == 2) ? 14 : 7;
        const int C = (lv == 0) ? 64 : (lv == 1) ? 128 : (lv == 2) ? 256 : 512;
        const float scale = (float)H / 224.0f;   // exact power-of-2 ratio
        const float x = h * scale, y = w * scale;
        const float x1f = floorf(x), x2f = fminf(ceilf(x), (float)(H - 1));
        const float y1f = floorf(y), y2f = fminf(ceilf(y), (float)(H - 1));
        const int xi1 = (int)x1f, xi2 = (int)x2f;
        const int yi1 = (int)y1f, yi2 = (int)y2f;

        s_w[pt][lv][0] = (x2f - x) * (y2f - y);   // w11 -> Q11 (xi1,yi1)
        s_w[pt][lv][1] = (x - x1f) * (y2f - y);   // w21 -> Q21 (xi2,yi1)
        s_w[pt][lv][2] = (x2f - x) * (y - y1f);   // w12 -> Q12 (xi1,yi2)
        s_w[pt][lv][3] = (x - x1f) * (y - y1f);   // w22 -> Q22 (xi2,yi2)

        const float* f = (lv == 0) ? f1 : (lv == 1) ? f2 : (lv == 2) ? f3 : f4;
        s_q[pt][lv][0] = f + (size_t)(xi1 * H + yi1) * C;
        s_q[pt][lv][1] = f + (size_t)(xi2 * H + yi1) * C;
        s_q[pt][lv][2] = f + (size_t)(xi1 * H + yi2) * C;
        s_q[pt][lv][3] = f + (size_t)(xi2 * H + yi2) * C;
    }
    // coords straight to global (cols 0..2 of each row) -- only on the main
    // path; the tail path writes them itself.
    if (npts == PTS && t >= 64 && t < 64 + 3 * PTS) {
        const int i = t - 64;
        out[(size_t)(p0 + i / 3) * ROWF + (i % 3)] = coords[p0 * 3 + i];
    }
    __syncthreads();

    if (npts == PTS) {
        // ---- main: gather + blend + DIRECT unaligned nontemporal store ----
        for (int gf = t; gf < PTS * GP2; gf += 256) {
            const int pt = gf / GP2;
            const int g2 = gf - pt * GP2;
            const int g  = g2 * 2;          // 4-float group index (even)
            // level ranges (4-float groups): [0,16) L1, [16,48) L2,
            // [48,112) L3, [112,240) L4.  g even => (g,g+1) never split.
            const int lv = (g >= 16) + (g >= 48) + (g >= 112);
            const int c4 = g - ((lv == 0) ? 0 : (lv == 1) ? 16 : (lv == 2) ? 48 : 112);

            const float4 wv = *(const float4*)&s_w[pt][lv][0];
            const fx4* q11 = (const fx4*)s_q[pt][lv][0];
            const fx4* q21 = (const fx4*)s_q[pt][lv][1];
            const fx4* q12 = (const fx4*)s_q[pt][lv][2];
            const fx4* q22 = (const fx4*)s_q[pt][lv][3];

            const fx4 a0 = q11[c4],     b0 = q21[c4],     c0 = q12[c4],     d0 = q22[c4];
            const fx4 a1 = q11[c4 + 1], b1 = q21[c4 + 1], c1 = q12[c4 + 1], d1 = q22[c4 + 1];

            const fx4 r0 = blend4(wv, a0, b0, c0, d0);
            const fx4 r1 = blend4(wv, a1, b1, c1, d1);

            float* o = out + (size_t)(p0 + pt) * ROWF + 3 + 4 * g;
            __builtin_nontemporal_store(r0, (fx4u*)o);
            __builtin_nontemporal_store(r1, (fx4u*)(o + 4));
        }
    } else {
        // ---- tail block (N % PTS != 0): scalar per-float fallback ----
        for (int i = t; i < npts * ROWF; i += 256) {
            const int pt = i / ROWF;
            const int r  = i - pt * ROWF;
            float v;
            if (r < 3) {
                v = coords[(p0 + pt) * 3 + r];
            } else {
                const int c  = r - 3;
                const int lv = (c >= 64) + (c >= 192) + (c >= 448);
                const int cc = c - ((lv == 0) ? 0 : (lv == 1) ? 64 : (lv == 2) ? 192 : 448);
                v = s_w[pt][lv][0] * s_q[pt][lv][0][cc]
                  + s_w[pt][lv][1] * s_q[pt][lv][1][cc]
                  + s_w[pt][lv][2] * s_q[pt][lv][2][cc]
                  + s_w[pt][lv][3] * s_q[pt][lv][3][cc];
            }
            out[(size_t)p0 * ROWF + i] = v;
        }
    }
}

extern "C" void kernel_launch(void* const* d_in, const int* in_sizes, int n_in,
                              void* d_out, int out_size, void* d_ws, size_t ws_size,
                              hipStream_t stream) {
    const float* coords = (const float*)d_in[0];
    const float* f1 = (const float*)d_in[1];
    const float* f2 = (const float*)d_in[2];
    const float* f3 = (const float*)d_in[3];
    const float* f4 = (const float*)d_in[4];
    float* out = (float*)d_out;
    const int N = in_sizes[0] / 3;

    const int blocks = (N + PTS - 1) / PTS;
    graphproj_kernel<<<blocks, 256, 0, stream>>>(coords, f1, f2, f3, f4, out, N);
}